// Round 1
// 630.800 us; speedup vs baseline: 1.2099x; 1.2099x over previous
//
#include <hip/hip_runtime.h>
#include <math.h>

// ---------------------------------------------------------------------------
// Problem constants
#define SIZE 128
#define WIN 32
#define HALF 16
#define B 8
#define C 64
#define N (SIZE*SIZE)        // 16384
#define BCN 8388608          // B*C*N
#define BV 97                // box VALID output size (128-32+1)

// Output offsets (floats) — tuple order:
// feat1_apply, feat2_apply, grid1, grid2, feat1_edge, feat2_color,
// f1_attn, f2_attn, feat1, feat2
#define O_APPLY1   0
#define O_APPLY2   8388608
#define O_GRID1    16777216
#define O_GRID2    17039360
#define O_EDGEF    17301504
#define O_COLORF   25690112
#define O_ATTN1    34078720
#define O_ATTN2    34111488
#define O_FEAT1    34144256
#define O_FEAT2    42532864
// total 50921472 floats

// Workspace offsets (floats)
#define WS_C1      0         // 8*16384
#define WS_C2      131072
#define WS_COLSUM  262144    // 8*97*128 = 99328
#define WS_XY      361472    // 32 ints
#define WS_MOM     361600    // 8*9*16384 = 1179648
#define WS_EDGE    1541248   // 8*16384
#define WS_LOG1    1672320   // 32768
#define WS_LOG2    1705088   // 32768
#define WS_BN      1737856   // 256

#define NEGINF (-3.402823466e+38f)

typedef unsigned __int128 u128;

// ---------------------------------------------------------------------------
__global__ void k_init(float* __restrict__ p, int n) {
  int i = blockIdx.x * 256 + threadIdx.x;
  if (i < n) p[i] = 0.f;
}

// bilinear 64->128 upsample of both cams
__global__ __launch_bounds__(256) void k_resize_cam(
    const float* __restrict__ cam1, const float* __restrict__ cam2,
    float* __restrict__ c1, float* __restrict__ c2) {
  int idx = blockIdx.x * 256 + threadIdx.x;      // 2*131072
  int which = idx >> 17;
  int rem = idx & 131071;
  int b = rem >> 14, i = (rem >> 7) & 127, j = rem & 127;
  const float* s = (which ? cam2 : cam1) + b * 4096;
  float fy = fminf(fmaxf(0.5f * (float)i - 0.25f, 0.f), 63.f);
  float fx = fminf(fmaxf(0.5f * (float)j - 0.25f, 0.f), 63.f);
  int y0 = (int)fy; float ty = fy - (float)y0; int y1i = min(y0 + 1, 63);
  int x0 = (int)fx; float tx = fx - (float)x0; int x1i = min(x0 + 1, 63);
  float v00 = s[y0 * 64 + x0],  v01 = s[y0 * 64 + x1i];
  float v10 = s[y1i * 64 + x0], v11 = s[y1i * 64 + x1i];
  float v = (1.f - ty) * ((1.f - tx) * v00 + tx * v01)
          + ty * ((1.f - tx) * v10 + tx * v11);
  (which ? c2 : c1)[rem] = v;
}

// Kogge-Stone occluded fill: all bits of m reachable from g through
// contiguous 1-runs of m (horizontal, both directions). 128-bit row.
__device__ __forceinline__ u128 hfill(u128 g, u128 m) {
  u128 p = m;
  g |= p & (g << 1);  p &= p << 1;
  g |= p & (g << 2);  p &= p << 2;
  g |= p & (g << 4);  p &= p << 4;
  g |= p & (g << 8);  p &= p << 8;
  g |= p & (g << 16); p &= p << 16;
  g |= p & (g << 32); p &= p << 32;
  g |= p & (g << 64);
  p = m;
  g |= p & (g >> 1);  p &= p >> 1;
  g |= p & (g >> 2);  p &= p >> 2;
  g |= p & (g >> 4);  p &= p >> 4;
  g |= p & (g >> 8);  p &= p >> 8;
  g |= p & (g >> 16); p &= p >> 16;
  g |= p & (g >> 32); p &= p >> 32;
  g |= p & (g >> 64);
  return g;
}

// _locate_region per batch: LDS-staged argmax + gradient mask +
// row-parallel Kogge-Stone flood fill + bbox
__global__ __launch_bounds__(256) void k_locate(const float* __restrict__ c1,
                                                int* __restrict__ xy) {
  int b = blockIdx.x;
  const float* c = c1 + b * N;
  int tid = threadIdx.x;
  __shared__ float sc[N];                       // 64 KB cam tile
  __shared__ float sv[256]; __shared__ int si[256];
  __shared__ unsigned int maskw[512];
  __shared__ unsigned long long glo[128], ghi[128];
  __shared__ unsigned long long rowany[2];
  __shared__ int s_changed, s_xm, s_ym, s_ok;

  // ---- load tile into LDS (coalesced float4) + per-thread argmax
  float bv = NEGINF; int bi = 0;
  const float4* c4 = (const float4*)c;
  float4* sc4 = (float4*)sc;
  #pragma unroll
  for (int k = 0; k < 16; ++k) {
    int i4 = k * 256 + tid;
    float4 v = c4[i4];
    sc4[i4] = v;
    int base = i4 * 4;
    if (v.x > bv) { bv = v.x; bi = base; }
    if (v.y > bv) { bv = v.y; bi = base + 1; }
    if (v.z > bv) { bv = v.z; bi = base + 2; }
    if (v.w > bv) { bv = v.w; bi = base + 3; }
  }
  sv[tid] = bv; si[tid] = bi;
  __syncthreads();
  for (int s = 128; s; s >>= 1) {
    if (tid < s) {
      float ov = sv[tid + s]; int oi = si[tid + s];
      if (ov > sv[tid] || (ov == sv[tid] && oi < si[tid])) { sv[tid] = ov; si[tid] = oi; }
    }
    __syncthreads();
  }
  if (tid == 0) { s_xm = si[0] >> 7; s_ym = si[0] & 127; }

  // ---- gradient-magnitude mask, bit-packed (4 words/row), from LDS
  #pragma unroll
  for (int q = 0; q < 2; ++q) {
    int w = tid + q * 256;
    int row = w >> 2, cb = (w & 3) * 32;
    unsigned int m = 0;
    for (int bit = 0; bit < 32; ++bit) {
      int i = row, j = cb + bit;
      float gx_, gy_;
      if (i == 0)        gx_ = sc[128 + j] - sc[j];
      else if (i == 127) gx_ = sc[127 * 128 + j] - sc[126 * 128 + j];
      else               gx_ = 0.5f * (sc[(i + 1) * 128 + j] - sc[(i - 1) * 128 + j]);
      if (j == 0)        gy_ = sc[i * 128 + 1] - sc[i * 128];
      else if (j == 127) gy_ = sc[i * 128 + 127] - sc[i * 128 + 126];
      else               gy_ = 0.5f * (sc[i * 128 + j + 1] - sc[i * 128 + j - 1]);
      if (hypotf(gx_, gy_) < 0.2f) m |= (1u << bit);
    }
    maskw[w] = m;
  }
  __syncthreads();
  if (tid == 0) {
    int w = (s_xm << 2) + (s_ym >> 5), bit = s_ym & 31;
    s_ok = (maskw[w] >> bit) & 1;
  }
  __syncthreads();

  // ---- flood fill: one thread per row, 128-bit row masks
  int r = tid;
  u128 m = 0, g = 0;
  if (tid < 128) {
    m = ((u128)maskw[r * 4])
      | ((u128)maskw[r * 4 + 1] << 32)
      | ((u128)maskw[r * 4 + 2] << 64)
      | ((u128)maskw[r * 4 + 3] << 96);
    if (s_ok && r == s_xm) g = ((u128)1) << s_ym;
    g = hfill(g, m);
  }
  for (;;) {
    if (tid == 0) s_changed = 0;
    if (tid < 128) { glo[r] = (unsigned long long)g; ghi[r] = (unsigned long long)(g >> 64); }
    __syncthreads();
    if (tid < 128) {
      u128 gn = g;
      if (r > 0)   gn |= ((u128)glo[r - 1]) | ((u128)ghi[r - 1] << 64);
      if (r < 127) gn |= ((u128)glo[r + 1]) | ((u128)ghi[r + 1] << 64);
      gn &= m;
      gn = hfill(gn, m);
      if (gn != g) { g = gn; s_changed = 1; }
    }
    __syncthreads();
    if (!s_changed) break;
  }

  // ---- bbox: row extents via ballot, column extents via OR of rows
  if (tid < 128) {
    unsigned long long ba = __ballot(g != 0);   // wave-uniform branch
    if ((tid & 63) == 0) rowany[tid >> 6] = ba;
    glo[r] = (unsigned long long)g; ghi[r] = (unsigned long long)(g >> 64);
  }
  __syncthreads();
  if (tid == 0) {
    unsigned long long r0 = rowany[0], r1 = rowany[1];
    unsigned long long cl = 0, ch = 0;
    for (int i = 0; i < 128; ++i) { cl |= glo[i]; ch |= ghi[i]; }
    int rs = 0, re = 0, cs = 0, ce = 0;
    if (r0 | r1) {
      rs = r0 ? (__ffsll(r0) - 1) : 64 + (__ffsll(r1) - 1);
      re = r1 ? 128 - __clzll(r1) : 64 - __clzll(r0);
      cs = cl ? (__ffsll(cl) - 1) : 64 + (__ffsll(ch) - 1);
      ce = ch ? 128 - __clzll(ch) : 64 - __clzll(cl);
    }
    int x1, y1;
    if (s_ok) { x1 = (rs + re) >> 1; y1 = (cs + ce) >> 1; }
    else      { x1 = s_xm;           y1 = s_ym; }
    xy[b] = x1; xy[8 + b] = y1;
  }
}

// column sums (32 rows) of c2: colsum[b][r in 0..96][c in 0..127]
__global__ __launch_bounds__(256) void k_colsum(const float* __restrict__ c2,
                                                float* __restrict__ cs) {
  int idx = blockIdx.x * 256 + threadIdx.x;
  if (idx >= B * BV * 128) return;
  int cc = idx & 127, r = (idx >> 7) % BV, b = idx / (BV * 128);
  const float* s = c2 + b * N + cc;
  float acc = 0.f;
  #pragma unroll
  for (int dy = 0; dy < WIN; ++dy) acc += s[(r + dy) * 128];
  cs[idx] = acc;
}

// 32x32 box argmax on c2 -> x2,y2
__global__ __launch_bounds__(256) void k_boxargmax(const float* __restrict__ colsum,
                                                   int* __restrict__ xy) {
  int b = blockIdx.x, tid = threadIdx.x;
  const float* cs = colsum + b * BV * 128;
  float bv = NEGINF; int bi = 0;
  for (int p = tid; p < BV * BV; p += 256) {
    int r = p / BV, cc = p % BV;
    const float* row = cs + r * 128 + cc;
    float s = 0.f;
    #pragma unroll
    for (int dx = 0; dx < WIN; ++dx) s += row[dx];
    if (s > bv) { bv = s; bi = p; }
  }
  __shared__ float sv[256]; __shared__ int si[256];
  sv[tid] = bv; si[tid] = bi;
  __syncthreads();
  for (int s = 128; s; s >>= 1) {
    if (tid < s) {
      float ov = sv[tid + s]; int oi = si[tid + s];
      if (ov > sv[tid] || (ov == sv[tid] && oi < si[tid])) { sv[tid] = ov; si[tid] = oi; }
    }
    __syncthreads();
  }
  if (tid == 0) { xy[16 + b] = si[0] / BV + HALF; xy[24 + b] = si[0] % BV + HALF; }
}

// grids -> outputs 2,3
__global__ __launch_bounds__(256) void k_grids(const int* __restrict__ xy,
                                               float* __restrict__ g1, float* __restrict__ g2) {
  int idx = blockIdx.x * 256 + threadIdx.x;   // B*N
  int b = idx >> 14, h = (idx >> 7) & 127, w = idx & 127;
  float x1 = (float)xy[b], y1 = (float)xy[8 + b];
  float x2 = (float)xy[16 + b], y2 = (float)xy[24 + b];
  float bx = (2.f * (float)w + 1.f) / 128.f - 1.f;
  float by = (2.f * (float)h + 1.f) / 128.f - 1.f;
  float m1x = (x1 - x2) / 64.f, m1y = (y1 - y2) / 64.f;
  g1[idx * 2]     = bx + m1x; g1[idx * 2 + 1] = by + m1y;
  g2[idx * 2]     = bx - m1x; g2[idx * 2 + 1] = by - m1y;
}

// color moments of f_e fused with 512->128 resize (avg of 2x2 at 4i+1,4i+2)
__global__ __launch_bounds__(256) void k_moments(const float* __restrict__ fe,
                                                 float* __restrict__ mom) {
  int idx = blockIdx.x * 256 + threadIdx.x;   // 8*3*16384
  int j = idx & 127, i = (idx >> 7) & 127, ch = (idx >> 14) % 3, b = idx / (3 * N);
  const float* src = fe + (size_t)(b * 3 + ch) * 262144;
  float s1a[6], s2a[6], s3a[6], s1b[6], s2b[6], s3b[6];
  #pragma unroll
  for (int t = 0; t < 6; ++t) {
    float a1 = 0, a2 = 0, a3 = 0, b1 = 0, b2 = 0, b3 = 0;
    int x = 4 * j - 1 + t;
    bool xo = (x >= 0 && x < 512);
    #pragma unroll
    for (int r = 0; r < 6; ++r) {
      int y = 4 * i - 1 + r;
      float v = (xo && y >= 0 && y < 512) ? src[y * 512 + x] : 0.f;
      float v2 = v * v, v3 = v2 * v;
      if (r < 5) { a1 += v; a2 += v2; a3 += v3; }
      if (r > 0) { b1 += v; b2 += v2; b3 += v3; }
    }
    s1a[t] = a1; s2a[t] = a2; s3a[t] = a3;
    s1b[t] = b1; s2b[t] = b2; s3b[t] = b3;
  }
  float am = 0, av = 0, as = 0;
  #pragma unroll
  for (int py = 0; py < 2; ++py) {
    #pragma unroll
    for (int px = 0; px < 2; ++px) {
      float s1 = 0, s2 = 0, s3 = 0;
      #pragma unroll
      for (int t = 0; t < 5; ++t) {
        s1 += py ? s1b[px + t] : s1a[px + t];
        s2 += py ? s2b[px + t] : s2a[px + t];
        s3 += py ? s3b[px + t] : s3a[px + t];
      }
      float mean = s1 / 25.f;
      float var  = (s2 - 25.f * mean * mean) / 24.f;
      float m3   = (s3 - 3.f * mean * s2 + 50.f * mean * mean * mean) / 25.f;
      float sq   = sqrtf(fmaxf(var, 0.f));
      float skew = m3 / (sq * sq * sq + 1e-6f);
      am += mean; av += var; as += skew;
    }
  }
  int base = (b * 9 + ch) * N + i * 128 + j;
  mom[base]         = 0.25f * am;
  mom[base + 3 * N] = 0.25f * av;
  mom[base + 6 * N] = 0.25f * as;
}

// edge extraction of f_g (channel-sum; separable Gauss-deriv 5x5) fused with resize
__global__ __launch_bounds__(256) void k_edge(const float* __restrict__ fg,
                                              float* __restrict__ edge) {
  int idx = blockIdx.x * 256 + threadIdx.x;   // 8*16384
  int j = idx & 127, i = (idx >> 7) & 127, b = idx >> 14;
  const float* s0 = fg + (size_t)b * 3 * 262144;
  const float INV2PI = 0.15915494309189535f;
  float wg[5], ug[5];
  #pragma unroll
  for (int t = 0; t < 5; ++t) {
    float a = (float)t - 2.f;
    float e = expf(-0.5f * a * a);
    wg[t] = e; ug[t] = -a * e;
  }
  float rAa[6], rAb[6], rBa[6], rBb[6];
  #pragma unroll
  for (int t = 0; t < 6; ++t) {
    float aa = 0, ab = 0, ba = 0, bb = 0;
    int x = 4 * j - 1 + t;
    bool xo = (x >= 0 && x < 512);
    #pragma unroll
    for (int r = 0; r < 6; ++r) {
      int y = 4 * i - 1 + r;
      float v = 0.f;
      if (xo && y >= 0 && y < 512) {
        int o = y * 512 + x;
        v = s0[o] + s0[262144 + o] + s0[524288 + o];
      }
      if (r < 5) { aa += v * wg[r]; ba += v * ug[r]; }
      if (r > 0) { ab += v * wg[r - 1]; bb += v * ug[r - 1]; }
    }
    rAa[t] = aa; rAb[t] = ab; rBa[t] = ba; rBb[t] = bb;
  }
  float acc = 0.f;
  #pragma unroll
  for (int py = 0; py < 2; ++py) {
    #pragma unroll
    for (int px = 0; px < 2; ++px) {
      float h = 0, v = 0;
      #pragma unroll
      for (int t = 0; t < 5; ++t) {
        float A  = py ? rAb[px + t] : rAa[px + t];
        float Bw = py ? rBb[px + t] : rBa[px + t];
        h += A * ug[t];
        v += Bw * wg[t];
      }
      h *= INV2PI; v *= INV2PI;
      acc += tanhf(sqrtf(h * h + v * v + 1e-8f));
    }
  }
  edge[idx] = 0.25f * acc;
}

// feat1_edge = clip(conv3x3(edge(1ch), sum_i conv1_w) + b, 0, 6)
__global__ __launch_bounds__(256) void k_conv1(const float* __restrict__ edge,
                                               const float* __restrict__ w,
                                               const float* __restrict__ bias,
                                               float* __restrict__ out) {
  int b = blockIdx.x >> 6, tile = blockIdx.x & 63;
  int ti0 = (tile >> 3) * 16, tj0 = (tile & 7) * 16;
  __shared__ float et[18 * 18];
  __shared__ float ws1[64 * 9];
  int tid = threadIdx.x;
  for (int l = tid; l < 324; l += 256) {
    int r = l / 18, cc = l % 18;
    int gi = ti0 + r - 1, gj = tj0 + cc - 1;
    et[l] = (gi >= 0 && gi < 128 && gj >= 0 && gj < 128) ? edge[b * N + gi * 128 + gj] : 0.f;
  }
  for (int l = tid; l < 576; l += 256) {
    int o = l / 9, t = l % 9;
    ws1[l] = w[o * 27 + t] + w[o * 27 + 9 + t] + w[o * 27 + 18 + t];
  }
  __syncthreads();
  int i = tid >> 4, j = tid & 15;
  float* o = out + (size_t)b * C * N + (ti0 + i) * 128 + tj0 + j;
  for (int oc = 0; oc < C; ++oc) {
    float acc = bias[oc];
    #pragma unroll
    for (int t = 0; t < 9; ++t)
      acc += ws1[oc * 9 + t] * et[(i + t / 3) * 18 + (j + t % 3)];
    o[oc * N] = fminf(fmaxf(acc, 0.f), 6.f);
  }
}

// feat2_color = conv3x3(moments 9ch) + b (no clip)
__global__ __launch_bounds__(256) void k_conv2(const float* __restrict__ mom,
                                               const float* __restrict__ w,
                                               const float* __restrict__ bias,
                                               float* __restrict__ out) {
  int b = blockIdx.x >> 6, tile = blockIdx.x & 63;
  int ti0 = (tile >> 3) * 16, tj0 = (tile & 7) * 16;
  __shared__ float mt[9 * 324];
  __shared__ float w2s[64 * 81];
  int tid = threadIdx.x;
  for (int l = tid; l < 9 * 324; l += 256) {
    int ic = l / 324, rem = l % 324, r = rem / 18, cc = rem % 18;
    int gi = ti0 + r - 1, gj = tj0 + cc - 1;
    mt[l] = (gi >= 0 && gi < 128 && gj >= 0 && gj < 128) ? mom[(b * 9 + ic) * N + gi * 128 + gj] : 0.f;
  }
  for (int l = tid; l < 64 * 81; l += 256) w2s[l] = w[l];
  __syncthreads();
  int i = tid >> 4, j = tid & 15;
  float* o = out + (size_t)b * C * N + (ti0 + i) * 128 + tj0 + j;
  for (int oc = 0; oc < C; ++oc) {
    float acc = bias[oc];
    #pragma unroll
    for (int ic = 0; ic < 9; ++ic) {
      #pragma unroll
      for (int t = 0; t < 9; ++t)
        acc += w2s[oc * 81 + ic * 9 + t] * mt[ic * 324 + (i + t / 3) * 18 + (j + t % 3)];
    }
    o[oc * N] = acc;
  }
}

// logits[b][c][d] += sum over window of a_shifted[c] * bsrc[d]
__global__ __launch_bounds__(256) void k_logits(const float* __restrict__ aBase,
                                                const float* __restrict__ bBase,
                                                float* __restrict__ out,
                                                const int* __restrict__ xy, int mode) {
  int b = blockIdx.x >> 4, sl = blockIdx.x & 15;
  int x1 = xy[b], y1 = xy[8 + b], x2 = xy[16 + b], y2 = xy[24 + b];
  int dyh, dxw, rlo, rhi, clo, chi;
  if (mode == 0) {
    dyh = y1 - y2; dxw = x1 - x2;
    rlo = max(x1 - HALF, 0); rhi = min(x1 + HALF, SIZE);
    clo = max(y1 - HALF, 0); chi = min(y1 + HALF, SIZE);
  } else {
    dyh = y2 - y1; dxw = x2 - x1;
    rlo = max(x2 - HALF, 0); rhi = min(x2 + HALF, SIZE);
    clo = max(y2 - HALF, 0); chi = min(y2 + HALF, SIZE);
  }
  int hlo = max(0, rlo - dyh), hhi = min(SIZE, rhi - dyh);
  int wlo = max(0, clo - dxw), whi = min(SIZE, chi - dxw);
  int wn = whi - wlo, hn = hhi - hlo;
  int npos = (wn > 0 && hn > 0) ? wn * hn : 0;
  if (sl * 64 >= npos) return;

  __shared__ float aS[64][65];
  __shared__ float bS[64][65];
  int tid = threadIdx.x;
  const float* aB = aBase + (size_t)b * C * N;
  const float* bB = bBase + (size_t)b * C * N;
  for (int l = tid; l < 4096; l += 256) {
    int ch = l >> 6, k = l & 63;
    int p = sl * 64 + k;
    float av = 0.f, bv = 0.f;
    if (p < npos) {
      int h = hlo + p / wn, w = wlo + p % wn;
      av = aB[ch * N + (h + dyh) * 128 + (w + dxw)];
      bv = bB[ch * N + h * 128 + w];
    }
    aS[ch][k] = av; bS[ch][k] = bv;
  }
  __syncthreads();
  int ci = (tid >> 4) << 2, di = (tid & 15) << 2;
  float acc[4][4] = {};
  #pragma unroll 4
  for (int k = 0; k < 64; ++k) {
    float a0 = aS[ci][k], a1 = aS[ci + 1][k], a2 = aS[ci + 2][k], a3 = aS[ci + 3][k];
    float b0 = bS[di][k], b1 = bS[di + 1][k], b2 = bS[di + 2][k], b3 = bS[di + 3][k];
    acc[0][0] += a0 * b0; acc[0][1] += a0 * b1; acc[0][2] += a0 * b2; acc[0][3] += a0 * b3;
    acc[1][0] += a1 * b0; acc[1][1] += a1 * b1; acc[1][2] += a1 * b2; acc[1][3] += a1 * b3;
    acc[2][0] += a2 * b0; acc[2][1] += a2 * b1; acc[2][2] += a2 * b2; acc[2][3] += a2 * b3;
    acc[3][0] += a3 * b0; acc[3][1] += a3 * b1; acc[3][2] += a3 * b2; acc[3][3] += a3 * b3;
  }
  float* o = out + b * 4096;
  #pragma unroll
  for (int u = 0; u < 4; ++u)
    #pragma unroll
    for (int v = 0; v < 4; ++v)
      atomicAdd(&o[(ci + u) * 64 + (di + v)], acc[u][v]);
}

// softmax over last dim (64) of both logit tensors
__global__ void k_softmax(const float* __restrict__ l1, const float* __restrict__ l2,
                          float* __restrict__ o6, float* __restrict__ o7) {
  int row = blockIdx.x;            // 0..511
  const float* src = blockIdx.y ? l2 : l1;
  float* dst = blockIdx.y ? o7 : o6;
  int lane = threadIdx.x;
  float v = src[row * 64 + lane];
  float mx = v;
  for (int off = 32; off; off >>= 1) mx = fmaxf(mx, __shfl_xor(mx, off));
  float e = expf(v - mx);
  float s = e;
  for (int off = 32; off; off >>= 1) s += __shfl_xor(s, off);
  dst[row * 64 + lane] = e / s;
}

// feat_apply_pre[b][c][n] = sum_d attn[b][c][d] * src[b][d][n]
__global__ __launch_bounds__(256) void k_apply(const float* __restrict__ a1,
                                               const float* __restrict__ s1_,
                                               float* __restrict__ d1,
                                               const float* __restrict__ a2,
                                               const float* __restrict__ s2_,
                                               float* __restrict__ d2) {
  const float* attn; const float* src; float* dst;
  if (blockIdx.y == 0) { attn = a1; src = s1_; dst = d1; }
  else                 { attn = a2; src = s2_; dst = d2; }
  int b = blockIdx.x >> 6, chunk = blockIdx.x & 63;
  int n0 = chunk * 256 + threadIdx.x;
  __shared__ __align__(16) float at[4096];
  for (int l = threadIdx.x; l < 4096; l += 256) at[l] = attn[b * 4096 + l];
  __syncthreads();
  const float* s = src + (size_t)b * C * N + n0;
  float v[64];
  #pragma unroll
  for (int d = 0; d < 64; ++d) v[d] = s[d * N];
  float* o = dst + (size_t)b * C * N + n0;
  for (int c = 0; c < 64; ++c) {
    const float4* ar = (const float4*)(at + c * 64);
    float acc = 0.f;
    #pragma unroll
    for (int q = 0; q < 16; ++q) {
      float4 w4 = ar[q];
      acc += w4.x * v[4 * q] + w4.y * v[4 * q + 1] + w4.z * v[4 * q + 2] + w4.w * v[4 * q + 3];
    }
    o[c * N] = acc;
  }
}

// ---------------------------------------------------------------------------
// BN stats, two-stage tree reduction.
// Stage 1: grid (C, B, 2) = 1024 blocks; each block reduces one contiguous
// (b,c) plane of N floats with float4 loads -> partial (sum, sumsq).
// Stage 2: one block folds the 8 batch partials per (t,c) and emits
// mean / rstd into stats[].
__global__ __launch_bounds__(256) void k_bnstats1(const float* __restrict__ t0,
                                                  const float* __restrict__ t1,
                                                  float* __restrict__ part) {
  int c = blockIdx.x, b = blockIdx.y, t = blockIdx.z;
  const float* src = (t ? t1 : t0) + (size_t)(b * C + c) * N;
  const float4* s4 = (const float4*)src;
  float s = 0.f, ss = 0.f;
  #pragma unroll
  for (int k = 0; k < 16; ++k) {              // 4096 float4 / 256 threads
    float4 v = s4[k * 256 + threadIdx.x];
    s  += v.x + v.y + v.z + v.w;
    ss += v.x * v.x + v.y * v.y + v.z * v.z + v.w * v.w;
  }
  for (int off = 32; off; off >>= 1) {
    s  += __shfl_xor(s, off);
    ss += __shfl_xor(ss, off);
  }
  __shared__ float as[4], ass[4];
  int wave = threadIdx.x >> 6;
  if ((threadIdx.x & 63) == 0) { as[wave] = s; ass[wave] = ss; }
  __syncthreads();
  if (threadIdx.x == 0) {
    int idx = (t * C + c) * B + b;
    part[idx]        = as[0] + as[1] + as[2] + as[3];
    part[1024 + idx] = ass[0] + ass[1] + ass[2] + ass[3];
  }
}

__global__ void k_bnstats2(const float* __restrict__ part, float* __restrict__ stats) {
  int i = threadIdx.x;                         // 0..127
  int t = i >> 6, c = i & 63;
  float s = 0.f, ss = 0.f;
  #pragma unroll
  for (int b = 0; b < B; ++b) {
    int idx = (t * C + c) * B + b;
    s  += part[idx];
    ss += part[1024 + idx];
  }
  float mean = s / 131072.f;
  float var  = ss / 131072.f - mean * mean;
  stats[t * 128 + c]      = mean;
  stats[t * 128 + 64 + c] = 1.f / sqrtf(var + 1e-5f);
}

__global__ __launch_bounds__(256) void k_bnapply(float* __restrict__ t0, float* __restrict__ t1,
                                                 const float* __restrict__ stats,
                                                 const float* __restrict__ bw,
                                                 const float* __restrict__ bb) {
  int e = blockIdx.x * 256 + threadIdx.x;       // 0..BCN-1
  int t = blockIdx.y;
  float* p = t ? t1 : t0;
  int c = (e >> 14) & 63;
  float m = stats[t * 128 + c], r = stats[t * 128 + 64 + c];
  float y = (p[e] - m) * r * bw[c] + bb[c];
  p[e] = fminf(fmaxf(y, 0.f), 6.f);
}

// both feat copies in one kernel (replaces 2x hipMemcpyAsync D2D)
__global__ __launch_bounds__(256) void k_copy2(const float4* __restrict__ s1, float4* __restrict__ d1,
                                               const float4* __restrict__ s2, float4* __restrict__ d2) {
  int i = blockIdx.x * 256 + threadIdx.x;       // BCN/4
  d1[i] = s1[i];
  d2[i] = s2[i];
}

// ---------------------------------------------------------------------------
extern "C" void kernel_launch(void* const* d_in, const int* in_sizes, int n_in,
                              void* d_out, int out_size, void* d_ws, size_t ws_size,
                              hipStream_t stream) {
  const float* feat1   = (const float*)d_in[1];
  const float* feat2   = (const float*)d_in[2];
  const float* cam1    = (const float*)d_in[3];
  const float* cam2    = (const float*)d_in[4];
  const float* f_g     = (const float*)d_in[5];
  const float* f_e     = (const float*)d_in[6];
  const float* conv1_w = (const float*)d_in[7];
  const float* conv1_b = (const float*)d_in[8];
  const float* conv2_w = (const float*)d_in[9];
  const float* conv2_b = (const float*)d_in[10];
  const float* bn_w    = (const float*)d_in[11];
  const float* bn_b    = (const float*)d_in[12];

  float* out = (float*)d_out;
  float* w = (float*)d_ws;
  int* xy = (int*)(w + WS_XY);

  float* o0 = out + O_APPLY1;
  float* o1 = out + O_APPLY2;
  float* o2 = out + O_GRID1;
  float* o3 = out + O_GRID2;
  float* o4 = out + O_EDGEF;
  float* o5 = out + O_COLORF;
  float* o6 = out + O_ATTN1;
  float* o7 = out + O_ATTN2;
  float* o8 = out + O_FEAT1;
  float* o9 = out + O_FEAT2;

  // zero the atomic logits accumulators (LOG1 + LOG2 contiguous)
  k_init<<<(65536 + 255) / 256, 256, 0, stream>>>(w + WS_LOG1, 65536);

  k_resize_cam<<<1024, 256, 0, stream>>>(cam1, cam2, w + WS_C1, w + WS_C2);
  k_locate<<<B, 256, 0, stream>>>(w + WS_C1, xy);
  k_colsum<<<(B * BV * 128 + 255) / 256, 256, 0, stream>>>(w + WS_C2, w + WS_COLSUM);
  k_boxargmax<<<B, 256, 0, stream>>>(w + WS_COLSUM, xy);
  k_grids<<<B * N / 256, 256, 0, stream>>>(xy, o2, o3);

  k_moments<<<B * 3 * N / 256, 256, 0, stream>>>(f_e, w + WS_MOM);
  k_edge<<<B * N / 256, 256, 0, stream>>>(f_g, w + WS_EDGE);
  k_conv1<<<B * 64, 256, 0, stream>>>(w + WS_EDGE, conv1_w, conv1_b, o4);
  k_conv2<<<B * 64, 256, 0, stream>>>(w + WS_MOM, conv2_w, conv2_b, o5);

  k_copy2<<<BCN / 4 / 256, 256, 0, stream>>>((const float4*)feat1, (float4*)o8,
                                             (const float4*)feat2, (float4*)o9);

  // logits1 = f1m . feat2 ; logits2 = f2m . feat1
  k_logits<<<B * 16, 256, 0, stream>>>(o4, feat2, w + WS_LOG1, xy, 0);
  k_logits<<<B * 16, 256, 0, stream>>>(o5, feat1, w + WS_LOG2, xy, 1);

  k_softmax<<<dim3(B * C, 2), 64, 0, stream>>>(w + WS_LOG1, w + WS_LOG2, o6, o7);

  // feat1_apply = f2_attn @ feat1 ; feat2_apply = f1_attn @ feat2
  k_apply<<<dim3(B * 64, 2), 256, 0, stream>>>(o7, feat1, o0, o6, feat2, o1);

  // BN stats: two-stage tree (WS_LOG1 is dead after k_softmax — reuse it
  // for the 2048-float partial buffer)
  k_bnstats1<<<dim3(C, B, 2), 256, 0, stream>>>(o0, o1, w + WS_LOG1);
  k_bnstats2<<<1, 128, 0, stream>>>(w + WS_LOG1, w + WS_BN);

  k_bnapply<<<dim3(BCN / 256, 2), 256, 0, stream>>>(o0, o1, w + WS_BN, bn_w, bn_b);
}